// Round 8
// baseline (140.975 us; speedup 1.0000x reference)
//
#include <hip/hip_runtime.h>

// Pink-noise 6-pole IIR — warmup-tile parallel, ONE kernel, zero inter-block deps.
//
// Key fact: the slowest pole is 0.99886, so A^8192 = 8.7e-5 — the filter
// forgets its history in a few thousand samples. Each block computes one
// 8192-sample output tile preceded by an 8192-sample warmup scanned from zero
// state. Truncation error <= ~1e-5 (tolerance 7.8e-3); tile 0 of each channel
// is EXACT (zero prefix = true zero init).
//
// Round-6 lesson: 64 KB LDS (warmup+tile resident together) -> 2 blocks/CU ->
// phase-serialized (both pipes ~40%). Round-7 lesson: warmup read directly
// from global (128B/thread stride) latency-serializes the scan chain
// (hbm 2 TB/s, dur 63 µs). This round: ONE 32 KB buffer used TWICE —
//   phase A: stage warmup (coalesced) -> scan -> fold 8 wave totals into R.
//   phase B: stage output tile (prefetched into registers during phase A,
//            written after the phase-A reads complete) -> scan -> fold R in
//            -> recompute -> coalesced store.
// All global accesses coalesced float4; LDS 32.2 KB -> 3 blocks/CU.
//
// __launch_bounds__ 2nd arg acts as min BLOCKS/CU on this toolchain
// (r4: (512,2)->cap 128@108 live, r5: (512,4)->cap 64 + 580 MB spills,
// r3: (1024,4) crashed). (512,3) -> cap ~85 >= ~70-reg live set.

constexpr int kL = 65536;               // samples per channel
constexpr int kThr = 512;               // threads per block = 8 waves
constexpr int kWaves = kThr / 64;       // 8
constexpr int kT = 8192;                // samples per phase (tile & warmup)
constexpr int kW = 8192;                // warmup samples
constexpr int kPT = kT / kThr;          // 16 samples per thread per phase
constexpr int kTilesPerCh = kL / kT;    // 8

// XOR swizzle: bank-balances both the 16-strided chunk reads and the linear
// float4 access patterns; involution; keeps float4 groups (bits 0-1) intact.
__device__ __forceinline__ int swz(int i) {
    return i ^ (((i >> 5) & 7) << 2);
}

__global__ __launch_bounds__(kThr, 3) void pink_tile(
    const float* __restrict__ white, float* __restrict__ pink)
{
    constexpr float A[6] = {0.99886f, 0.99332f, 0.969f, 0.8665f, 0.55f, -0.7616f};
    constexpr float C[6] = {0.0555179f, 0.0750759f, 0.153852f, 0.3104856f, 0.5329522f, -0.016898f};
    constexpr float B6G = 0.115926f, DIRECT = 0.5362f, OUTG = 0.11f;

    __shared__ __align__(16) float buf[kT];      // 32 KiB, used twice
    __shared__ float swv[6][kWaves];

    const int tid = threadIdx.x, lane = tid & 63, wave = tid >> 6;
    const int ch = blockIdx.x / kTilesPerCh;
    const int tI = blockIdx.x % kTilesPerCh;
    const size_t outBase = (size_t)ch * kL + (size_t)tI * kT;

    // b6 seed for thread 0 (last warmup sample) — issue this load first.
    float pw0 = 0.f;
    if (tid == 0 && tI != 0) pw0 = white[outBase - 1];

    // Constants: mPT = A^16, pmL = (A^16)^lane, Mwv = (A^16)^64 = A^1024.
    // (Underflow to 0 for fast poles is numerically correct.)
    float mPT[6], pmL[6], Mwv[6];
    #pragma unroll
    for (int p = 0; p < 6; ++p) {
        float q = A[p];
        #pragma unroll
        for (int i = 0; i < 4; ++i) q *= q;          // A^16
        mPT[p] = q;
        float pm = 1.f, qq = q;
        #pragma unroll
        for (int b = 0; b < 6; ++b) { if ((lane >> b) & 1) pm *= qq; qq *= qq; }
        pmL[p] = pm;
        Mwv[p] = qq;                                  // (A^16)^64 = A^1024
    }

    float R[6] = {0.f, 0.f, 0.f, 0.f, 0.f, 0.f};      // warmup end state

    // Prefetch the output tile into registers (written to LDS in phase B —
    // the HBM latency hides under phase-A compute). Issue AFTER the warmup
    // loads so the LDS-write of warmup doesn't drain these.
    const float4* srcB = (const float4*)(white + outBase);
    float4 vB[4];

    if (tI != 0) {
        // ---- Phase A: warmup, fully coalesced through LDS ----
        const float4* srcA = (const float4*)(white + outBase - kW);
        float4 vA[4];
        #pragma unroll
        for (int k = 0; k < 4; ++k) vA[k] = srcA[tid + k * kThr];
        #pragma unroll
        for (int k = 0; k < 4; ++k) vB[k] = srcB[tid + k * kThr];
        #pragma unroll
        for (int k = 0; k < 4; ++k)
            *(float4*)&buf[swz(4 * (tid + k * kThr))] = vA[k];
        __syncthreads();             // warmup staged

        // Local scan (zero init) from LDS.
        float e[6] = {0.f, 0.f, 0.f, 0.f, 0.f, 0.f};
        #pragma unroll
        for (int kk = 0; kk < kPT / 4; ++kk) {
            const float4 x = *(const float4*)&buf[swz(kPT * tid + 4 * kk)];
            const float* xp = &x.x;
            #pragma unroll
            for (int j = 0; j < 4; ++j) {
                const float ww = xp[j];
                #pragma unroll
                for (int p = 0; p < 6; ++p) e[p] = fmaf(A[p], e[p], ww * C[p]);
            }
        }
        // Intra-wave affine scan (constant per-round multiplier).
        float mk[6];
        #pragma unroll
        for (int p = 0; p < 6; ++p) mk[p] = mPT[p];
        #pragma unroll
        for (int r = 0; r < 6; ++r) {
            const int off = 1 << r;
            float fe[6];
            #pragma unroll
            for (int p = 0; p < 6; ++p) fe[p] = __shfl_up(e[p], off);
            if (lane >= off) {
                #pragma unroll
                for (int p = 0; p < 6; ++p) e[p] = fmaf(mk[p], fe[p], e[p]);
            }
            #pragma unroll
            for (int p = 0; p < 6; ++p) mk[p] *= mk[p];
        }
        if (lane == 63) {
            #pragma unroll
            for (int p = 0; p < 6; ++p) swv[p][wave] = e[p];
        }
        __syncthreads();             // swv ready; all phase-A buf reads done

        // Fold the 8 wave totals -> warmup end state (uniform per thread).
        #pragma unroll
        for (int w2 = 0; w2 < kWaves; ++w2) {
            #pragma unroll
            for (int p = 0; p < 6; ++p) R[p] = fmaf(Mwv[p], R[p], swv[p][w2]);
        }
    } else {
        #pragma unroll
        for (int k = 0; k < 4; ++k) vB[k] = srcB[tid + k * kThr];
    }

    // ---- Phase B: output tile ----
    // (Phase-A swv reads completed before this barrier; buf reads before the
    // previous one — safe to overwrite both after it.)
    #pragma unroll
    for (int k = 0; k < 4; ++k)
        *(float4*)&buf[swz(4 * (tid + k * kThr))] = vB[k];
    __syncthreads();                 // tile staged

    // Local scan (zero init) from LDS.
    float e[6] = {0.f, 0.f, 0.f, 0.f, 0.f, 0.f};
    #pragma unroll
    for (int kk = 0; kk < kPT / 4; ++kk) {
        const float4 x = *(const float4*)&buf[swz(kPT * tid + 4 * kk)];
        const float* xp = &x.x;
        #pragma unroll
        for (int j = 0; j < 4; ++j) {
            const float ww = xp[j];
            #pragma unroll
            for (int p = 0; p < 6; ++p) e[p] = fmaf(A[p], e[p], ww * C[p]);
        }
    }
    // Previous white for the b6 delay line (read before recompute overwrites).
    const float pwl = (tid == 0) ? pw0 : buf[swz(kPT * tid - 1)];

    // Intra-wave affine scan.
    float mk[6];
    #pragma unroll
    for (int p = 0; p < 6; ++p) mk[p] = mPT[p];
    #pragma unroll
    for (int r = 0; r < 6; ++r) {
        const int off = 1 << r;
        float fe[6];
        #pragma unroll
        for (int p = 0; p < 6; ++p) fe[p] = __shfl_up(e[p], off);
        if (lane >= off) {
            #pragma unroll
            for (int p = 0; p < 6; ++p) e[p] = fmaf(mk[p], fe[p], e[p]);
        }
        #pragma unroll
        for (int p = 0; p < 6; ++p) mk[p] *= mk[p];
    }
    float ex[6];
    #pragma unroll
    for (int p = 0; p < 6; ++p) {
        ex[p] = __shfl_up(e[p], 1);
        if (lane == 0) ex[p] = 0.f;
    }
    if (lane == 63) {
        #pragma unroll
        for (int p = 0; p < 6; ++p) swv[p][wave] = e[p];
    }
    __syncthreads();                 // swv ready

    // Per-thread incoming state: fold R through previous waves, then this
    // lane's exclusive span.
    float b[6];
    #pragma unroll
    for (int p = 0; p < 6; ++p) {
        float X = R[p];
        #pragma unroll
        for (int w2 = 0; w2 < kWaves; ++w2)
            if (w2 < wave) X = fmaf(Mwv[p], X, swv[p][w2]);
        b[p] = fmaf(pmL[p], X, ex[p]);
    }
    float b6 = B6G * pwl;

    // Recompute + stage outputs in place (own chunk only; pwl captured above).
    #pragma unroll
    for (int kk = 0; kk < kPT / 4; ++kk) {
        const float4 x = *(const float4*)&buf[swz(kPT * tid + 4 * kk)];
        const float* xp = &x.x;
        float4 o;
        float* op = &o.x;
        #pragma unroll
        for (int j = 0; j < 4; ++j) {
            const float ww = xp[j];
            #pragma unroll
            for (int p = 0; p < 6; ++p) b[p] = fmaf(A[p], b[p], ww * C[p]);
            const float sum = ((b[0]+b[1]) + (b[2]+b[3])) + ((b[4]+b[5]) + b6);
            op[j] = fmaf(DIRECT, ww, sum) * OUTG;
            b6 = B6G * ww;
        }
        *(float4*)&buf[swz(kPT * tid + 4 * kk)] = o;
    }
    __syncthreads();                 // outputs staged

    // Coalesced store.
    float4* dst4 = (float4*)(pink + outBase);
    #pragma unroll
    for (int k = 0; k < 4; ++k)
        dst4[tid + k * kThr] = *(const float4*)&buf[swz(4 * (tid + k * kThr))];
}

extern "C" void kernel_launch(void* const* d_in, const int* in_sizes, int n_in,
                              void* d_out, int out_size, void* d_ws, size_t ws_size,
                              hipStream_t stream) {
    const float* white = (const float*)d_in[0];
    float* pink = (float*)d_out;
    const int nCh = in_sizes[0] / kL;                 // 256 channels
    const int nBlk = nCh * kTilesPerCh;               // 2048 blocks

    hipLaunchKernelGGL(pink_tile, dim3(nBlk), dim3(kThr), 0, stream,
                       white, pink);
}

// Round 9
// 128.239 us; speedup vs baseline: 1.0993x; 1.0993x over previous
//
#include <hip/hip_runtime.h>

// Pink-noise 6-pole IIR — warmup-tile parallel, ONE kernel, zero inter-block deps.
//
// Key fact: the slowest pole is 0.99886, so A^8192 = 8.7e-5 — the filter
// forgets its history in a few thousand samples. Each block computes one
// 8192-sample output tile preceded by an 8192-sample warmup scanned from zero
// state. Truncation error <= ~1e-5 (tolerance 7.8e-3); tile 0 of each channel
// is EXACT (zero prefix = true zero init).
//
// Occupancy model (rounds 4/5/7/8 evidence): wave slots are power-of-two
// quantized in VGPRs (<=64 regs -> 8 waves/SIMD, <=128 -> 4, <=256 -> 2).
// A 512-thread block = 8 waves, so >=3 blocks/CU REQUIRES VGPR <= 64 — any
// live value that doesn't fit spills to scratch (r8: 16-reg prefetch ->
// +134 MB spill traffic, VGPR 28). Therefore: no register prefetch; the
// two-phase structure's natural ~36-reg live set fits the 64-bin.
//
//   phase A: stage warmup (coalesced float4 -> swizzled LDS) -> 16-sample
//            local scan -> wave affine scan -> fold 8 wave totals into R.
//   phase B: stage output tile into the SAME 32 KB buffer -> scan -> fold R
//            + prior-wave totals -> recompute -> coalesced store.
// Phase-B load latency is covered by cross-block TLP (4 blocks/CU resident:
// LDS 33.3 KB x 4 = 133 KB <= 160; __launch_bounds__(512,4)).

constexpr int kL = 65536;               // samples per channel
constexpr int kThr = 512;               // threads per block = 8 waves
constexpr int kWaves = kThr / 64;       // 8
constexpr int kT = 8192;                // samples per phase (tile & warmup)
constexpr int kW = 8192;                // warmup samples
constexpr int kPT = kT / kThr;          // 16 samples per thread per phase
constexpr int kTilesPerCh = kL / kT;    // 8

// XOR swizzle: bank-balances both the 16-strided chunk reads and the linear
// float4 access patterns; involution; keeps float4 groups (bits 0-1) intact.
__device__ __forceinline__ int swz(int i) {
    return i ^ (((i >> 5) & 7) << 2);
}

__global__ __launch_bounds__(kThr, 4) void pink_tile(
    const float* __restrict__ white, float* __restrict__ pink)
{
    constexpr float A[6] = {0.99886f, 0.99332f, 0.969f, 0.8665f, 0.55f, -0.7616f};
    constexpr float C[6] = {0.0555179f, 0.0750759f, 0.153852f, 0.3104856f, 0.5329522f, -0.016898f};
    constexpr float B6G = 0.115926f, DIRECT = 0.5362f, OUTG = 0.11f;

    __shared__ __align__(16) float buf[kT];      // 32 KiB, used twice
    __shared__ float swv[6][kWaves];

    const int tid = threadIdx.x, lane = tid & 63, wave = tid >> 6;
    const int ch = blockIdx.x / kTilesPerCh;
    const int tI = blockIdx.x % kTilesPerCh;
    const size_t outBase = (size_t)ch * kL + (size_t)tI * kT;

    // b6 seed for thread 0 (last warmup sample).
    float pw0 = 0.f;
    if (tid == 0 && tI != 0) pw0 = white[outBase - 1];

    // Constants: mPT = A^16, pmL = (A^16)^lane, Mwv = (A^16)^64 = A^1024.
    // (Underflow to 0 for fast poles is numerically correct.)
    float mPT[6], pmL[6], Mwv[6];
    #pragma unroll
    for (int p = 0; p < 6; ++p) {
        float q = A[p];
        #pragma unroll
        for (int i = 0; i < 4; ++i) q *= q;          // A^16
        mPT[p] = q;
        float pm = 1.f, qq = q;
        #pragma unroll
        for (int b = 0; b < 6; ++b) { if ((lane >> b) & 1) pm *= qq; qq *= qq; }
        pmL[p] = pm;
        Mwv[p] = qq;                                  // (A^16)^64 = A^1024
    }

    float R[6] = {0.f, 0.f, 0.f, 0.f, 0.f, 0.f};      // warmup end state

    if (tI != 0) {
        // ---- Phase A: warmup, coalesced through LDS ----
        const float4* srcA = (const float4*)(white + outBase - kW);
        #pragma unroll
        for (int k = 0; k < 4; ++k) {
            const float4 x = srcA[tid + k * kThr];
            *(float4*)&buf[swz(4 * (tid + k * kThr))] = x;
        }
        __syncthreads();             // warmup staged

        // Local scan (zero init) from LDS.
        float e[6] = {0.f, 0.f, 0.f, 0.f, 0.f, 0.f};
        #pragma unroll
        for (int kk = 0; kk < kPT / 4; ++kk) {
            const float4 x = *(const float4*)&buf[swz(kPT * tid + 4 * kk)];
            const float* xp = &x.x;
            #pragma unroll
            for (int j = 0; j < 4; ++j) {
                const float ww = xp[j];
                #pragma unroll
                for (int p = 0; p < 6; ++p) e[p] = fmaf(A[p], e[p], ww * C[p]);
            }
        }
        // Intra-wave affine scan (totals only needed at lane 63).
        float mk[6];
        #pragma unroll
        for (int p = 0; p < 6; ++p) mk[p] = mPT[p];
        #pragma unroll
        for (int r = 0; r < 6; ++r) {
            const int off = 1 << r;
            float fe[6];
            #pragma unroll
            for (int p = 0; p < 6; ++p) fe[p] = __shfl_up(e[p], off);
            if (lane >= off) {
                #pragma unroll
                for (int p = 0; p < 6; ++p) e[p] = fmaf(mk[p], fe[p], e[p]);
            }
            #pragma unroll
            for (int p = 0; p < 6; ++p) mk[p] *= mk[p];
        }
        if (lane == 63) {
            #pragma unroll
            for (int p = 0; p < 6; ++p) swv[p][wave] = e[p];
        }
        __syncthreads();             // swv ready; all phase-A buf reads done

        // Fold the 8 wave totals -> warmup end state (uniform per thread).
        #pragma unroll
        for (int w2 = 0; w2 < kWaves; ++w2) {
            #pragma unroll
            for (int p = 0; p < 6; ++p) R[p] = fmaf(Mwv[p], R[p], swv[p][w2]);
        }
    }

    // ---- Phase B: output tile (loads issued here; TLP covers latency) ----
    const float4* srcB = (const float4*)(white + outBase);
    #pragma unroll
    for (int k = 0; k < 4; ++k) {
        const float4 x = srcB[tid + k * kThr];
        *(float4*)&buf[swz(4 * (tid + k * kThr))] = x;
    }
    __syncthreads();                 // tile staged

    // Local scan (zero init) from LDS.
    float e[6] = {0.f, 0.f, 0.f, 0.f, 0.f, 0.f};
    #pragma unroll
    for (int kk = 0; kk < kPT / 4; ++kk) {
        const float4 x = *(const float4*)&buf[swz(kPT * tid + 4 * kk)];
        const float* xp = &x.x;
        #pragma unroll
        for (int j = 0; j < 4; ++j) {
            const float ww = xp[j];
            #pragma unroll
            for (int p = 0; p < 6; ++p) e[p] = fmaf(A[p], e[p], ww * C[p]);
        }
    }
    // Previous white for the b6 delay line (read before recompute overwrites).
    const float pwl = (tid == 0) ? pw0 : buf[swz(kPT * tid - 1)];

    // Intra-wave affine scan.
    float mk[6];
    #pragma unroll
    for (int p = 0; p < 6; ++p) mk[p] = mPT[p];
    #pragma unroll
    for (int r = 0; r < 6; ++r) {
        const int off = 1 << r;
        float fe[6];
        #pragma unroll
        for (int p = 0; p < 6; ++p) fe[p] = __shfl_up(e[p], off);
        if (lane >= off) {
            #pragma unroll
            for (int p = 0; p < 6; ++p) e[p] = fmaf(mk[p], fe[p], e[p]);
        }
        #pragma unroll
        for (int p = 0; p < 6; ++p) mk[p] *= mk[p];
    }
    float ex[6];
    #pragma unroll
    for (int p = 0; p < 6; ++p) {
        ex[p] = __shfl_up(e[p], 1);
        if (lane == 0) ex[p] = 0.f;
    }
    if (lane == 63) {
        #pragma unroll
        for (int p = 0; p < 6; ++p) swv[p][wave] = e[p];
    }
    __syncthreads();                 // swv ready

    // Per-thread incoming state: fold R through previous waves, then this
    // lane's exclusive span.
    float b[6];
    #pragma unroll
    for (int p = 0; p < 6; ++p) {
        float X = R[p];
        #pragma unroll
        for (int w2 = 0; w2 < kWaves; ++w2)
            if (w2 < wave) X = fmaf(Mwv[p], X, swv[p][w2]);
        b[p] = fmaf(pmL[p], X, ex[p]);
    }
    float b6 = B6G * pwl;

    // Recompute + stage outputs in place (own chunk only; pwl captured above).
    #pragma unroll
    for (int kk = 0; kk < kPT / 4; ++kk) {
        const float4 x = *(const float4*)&buf[swz(kPT * tid + 4 * kk)];
        const float* xp = &x.x;
        float4 o;
        float* op = &o.x;
        #pragma unroll
        for (int j = 0; j < 4; ++j) {
            const float ww = xp[j];
            #pragma unroll
            for (int p = 0; p < 6; ++p) b[p] = fmaf(A[p], b[p], ww * C[p]);
            const float sum = ((b[0]+b[1]) + (b[2]+b[3])) + ((b[4]+b[5]) + b6);
            op[j] = fmaf(DIRECT, ww, sum) * OUTG;
            b6 = B6G * ww;
        }
        *(float4*)&buf[swz(kPT * tid + 4 * kk)] = o;
    }
    __syncthreads();                 // outputs staged

    // Coalesced store.
    float4* dst4 = (float4*)(pink + outBase);
    #pragma unroll
    for (int k = 0; k < 4; ++k)
        dst4[tid + k * kThr] = *(const float4*)&buf[swz(4 * (tid + k * kThr))];
}

extern "C" void kernel_launch(void* const* d_in, const int* in_sizes, int n_in,
                              void* d_out, int out_size, void* d_ws, size_t ws_size,
                              hipStream_t stream) {
    const float* white = (const float*)d_in[0];
    float* pink = (float*)d_out;
    const int nCh = in_sizes[0] / kL;                 // 256 channels
    const int nBlk = nCh * kTilesPerCh;               // 2048 blocks

    hipLaunchKernelGGL(pink_tile, dim3(nBlk), dim3(kThr), 0, stream,
                       white, pink);
}